// Round 1
// baseline (1020.495 us; speedup 1.0000x reference)
//
#include <hip/hip_runtime.h>

// LinearTPReadOut: out[n] = w_tp/(128*sqrt(3)) * sum_i a_i*b_i,
//   a_i = sum_u x[n, 128+3u+i]*w_lin[u,0],  b_i = sum_u x[n,128+3u+i]*w_lin[u,1]
// N=200000 rows of 1152 floats; only cols [128,512) are touched (1536B, 128B-aligned).

#define ROW_STRIDE 1152
#define OFF 128

__global__ __launch_bounds__(256) void lintp_kernel(
    const float* __restrict__ x,
    const float* __restrict__ w_lin,
    const float* __restrict__ w_tp,
    float* __restrict__ out,
    int n)
{
    const int tid = threadIdx.x;
    const int t   = tid & 15;                       // lane within 16-lane group
    const int row = blockIdx.x * 16 + (tid >> 4);   // one row per group

    // Preload this lane's weights (row-invariant): u = 8t .. 8t+7.
    // w_lin is (128,2) row-major -> indices 16t .. 16t+15, four float4s.
    float w0[8], w1[8];
    const float4* wv = (const float4*)(w_lin + 16 * t);
#pragma unroll
    for (int k = 0; k < 4; ++k) {
        float4 w = wv[k];
        w0[2 * k]     = w.x;  w1[2 * k]     = w.y;
        w0[2 * k + 1] = w.z;  w1[2 * k + 1] = w.w;
    }

    if (row >= n) return;

    // Lane covers positions p = 24t .. 24t+23 of the 384-float chunk.
    // Byte offset 512 + 96t within a 4608B row: 16B-aligned everywhere.
    const float4* xp = (const float4*)(x + (size_t)row * ROW_STRIDE + OFF + 24 * t);

    float a0 = 0.f, a1 = 0.f, a2 = 0.f, b0 = 0.f, b1 = 0.f, b2 = 0.f;
#pragma unroll
    for (int k = 0; k < 6; ++k) {
        float4 v = xp[k];
        float vv[4] = {v.x, v.y, v.z, v.w};
#pragma unroll
        for (int j = 0; j < 4; ++j) {
            const int p  = 4 * k + j;   // compile-time
            const int i  = p % 3;
            const int ur = p / 3;       // 0..7
            const float av = vv[j];
            if (i == 0)      { a0 += av * w0[ur]; b0 += av * w1[ur]; }
            else if (i == 1) { a1 += av * w0[ur]; b1 += av * w1[ur]; }
            else             { a2 += av * w0[ur]; b2 += av * w1[ur]; }
        }
    }

    // Butterfly reduce within the 16-lane group (masks < 16 never cross groups).
#pragma unroll
    for (int m = 1; m <= 8; m <<= 1) {
        a0 += __shfl_xor(a0, m); a1 += __shfl_xor(a1, m); a2 += __shfl_xor(a2, m);
        b0 += __shfl_xor(b0, m); b1 += __shfl_xor(b1, m); b2 += __shfl_xor(b2, m);
    }

    if (t == 0) {
        const float scale = w_tp[0] / (128.0f * 1.7320508075688772f); // wtp/(128*sqrt(3))
        out[row] = scale * (a0 * b0 + a1 * b1 + a2 * b2);
    }
}

extern "C" void kernel_launch(void* const* d_in, const int* in_sizes, int n_in,
                              void* d_out, int out_size, void* d_ws, size_t ws_size,
                              hipStream_t stream) {
    const float* x     = (const float*)d_in[0];
    const float* w_lin = (const float*)d_in[1];
    const float* w_tp  = (const float*)d_in[2];
    float* out = (float*)d_out;

    const int n = in_sizes[0] / ROW_STRIDE;          // 200000
    const int blocks = (n + 15) / 16;                // 16 rows per 256-thread block
    lintp_kernel<<<blocks, 256, 0, stream>>>(x, w_lin, w_tp, out, n);
}

// Round 2
// 1020.010 us; speedup vs baseline: 1.0005x; 1.0005x over previous
//
#include <hip/hip_runtime.h>

// LinearTPReadOut: out[n] = w_tp/(128*sqrt(3)) * sum_i a_i*b_i,
//   a_i = sum_u x[n, 128+3u+i]*w_lin[u,0],  b_i = sum_u x[n,128+3u+i]*w_lin[u,1]
// N=200000 rows of 1152 floats; only cols [128,512) touched (1536B, 128B-aligned).
// Roofline: 200000*1536B = 307 MB read @ ~6 TB/s -> ~52 us floor. Memory-bound.

#define ROW_STRIDE 1152
#define OFF 128

__global__ __launch_bounds__(256) void lintp_kernel(
    const float* __restrict__ x,
    const float* __restrict__ w_lin,
    const float* __restrict__ w_tp,
    float* __restrict__ out,
    int n)
{
    // 16 groups x 16 lanes; one row per group; 16 rows per block.
    __shared__ float4 tile[16 * 96];                 // 24 KB: [group][96 float4]

    const int tid = threadIdx.x;
    const int t   = tid & 15;                        // lane within group
    const int g   = tid >> 4;                        // group = local row
    const int row = blockIdx.x * 16 + g;

    // Preload lane-invariant weights: u = 8t..8t+7 -> w_lin flat [16t..16t+15].
    float w0[8], w1[8];
    const float4* wv = (const float4*)(w_lin + 16 * t);
#pragma unroll
    for (int k = 0; k < 4; ++k) {
        float4 w = wv[k];
        w0[2 * k]     = w.x;  w1[2 * k]     = w.y;
        w0[2 * k + 1] = w.z;  w1[2 * k + 1] = w.w;
    }

    // ---- Stage: fully coalesced global -> LDS ----
    // Lane t loads float4 indices {t, t+16, ..., t+80} of the row chunk:
    // 16 consecutive float4 (256B) per group per instruction.
    const int rowc = (row < n) ? row : (n - 1);      // clamp (n%16==0 normally)
    const float4* xp = (const float4*)(x + (size_t)rowc * ROW_STRIDE + OFF);
    float4 v[6];
#pragma unroll
    for (int k = 0; k < 6; ++k) v[k] = xp[t + 16 * k];   // 6 loads in flight
#pragma unroll
    for (int k = 0; k < 6; ++k) tile[g * 96 + t + 16 * k] = v[k];

    __syncthreads();

    // ---- Compute: lane t takes contiguous positions p = 24t .. 24t+23 ----
    // LDS read stride 96B across lanes -> 2-way bank aliasing only (free).
    float a0 = 0.f, a1 = 0.f, a2 = 0.f, b0 = 0.f, b1 = 0.f, b2 = 0.f;
#pragma unroll
    for (int k = 0; k < 6; ++k) {
        float4 c = tile[g * 96 + 6 * t + k];
        float cc[4] = {c.x, c.y, c.z, c.w};
#pragma unroll
        for (int j = 0; j < 4; ++j) {
            const int p  = 4 * k + j;    // compile-time 0..23
            const int i  = p % 3;
            const int ur = p / 3;        // 0..7
            const float av = cc[j];
            if (i == 0)      { a0 += av * w0[ur]; b0 += av * w1[ur]; }
            else if (i == 1) { a1 += av * w0[ur]; b1 += av * w1[ur]; }
            else             { a2 += av * w0[ur]; b2 += av * w1[ur]; }
        }
    }

    // Butterfly reduce within the 16-lane group (masks < 16 stay in-group).
#pragma unroll
    for (int m = 1; m <= 8; m <<= 1) {
        a0 += __shfl_xor(a0, m); a1 += __shfl_xor(a1, m); a2 += __shfl_xor(a2, m);
        b0 += __shfl_xor(b0, m); b1 += __shfl_xor(b1, m); b2 += __shfl_xor(b2, m);
    }

    if (t == 0 && row < n) {
        const float scale = w_tp[0] / (128.0f * 1.7320508075688772f);
        out[row] = scale * (a0 * b0 + a1 * b1 + a2 * b2);
    }
}

extern "C" void kernel_launch(void* const* d_in, const int* in_sizes, int n_in,
                              void* d_out, int out_size, void* d_ws, size_t ws_size,
                              hipStream_t stream) {
    const float* x     = (const float*)d_in[0];
    const float* w_lin = (const float*)d_in[1];
    const float* w_tp  = (const float*)d_in[2];
    float* out = (float*)d_out;

    const int n = in_sizes[0] / ROW_STRIDE;          // 200000
    const int blocks = (n + 15) / 16;                // 16 rows / 256-thread block
    lintp_kernel<<<blocks, 256, 0, stream>>>(x, w_lin, w_tp, out, n);
}